// Round 10
// baseline (158.824 us; speedup 1.0000x reference)
//
#include <hip/hip_runtime.h>
#include <math.h>

// LocalEnergyOpt R10: max-occupancy decomposition.
// R8/R9 falsified "staging style" and "trig cost" theories (43us invariant).
// Remaining model: compute is latency-bound at 16 waves/CU (4/SIMD) — ~6
// dependent terms/thread, 120-200cyc gather chains, nothing to hide them.
// Fix: one TERM per thread, 6144 blocks x 256 (one system spread over 24
// blocks, padded concat space -> wave-uniform type), no LDS staging, no
// syncthreads; gathers hit L2/L3-hot compact SoA. Compact = R5's full-grid
// window pass (row i -> floats 9i+5..8, one thread/row, 10000 blocks).
//  k1 prep:    resolve param tables (k,r0 | k,th0 | k,cos p0,sin p0,n)
//  k2 compact: features -> cc f32 / bq ushort4 / aq ushort4 / tq ushort8
//  k3 energy:  1 term/thread -> partial[c*256+b]  (XCD affinity: b%8)
//  k4 reduce:  out[b] = sum_c partial[c*256+b]

constexpr int BATCH  = 256;
constexpr int MAXLEN = 10000;
constexpr int NBT = 50, NAT = 100, NTT = 200;
constexpr float EPS = 1e-8f;
constexpr int NCH = 24;                     // 8 chunks per term type

// ws layout (bytes), ~22.9 MB
constexpr size_t OFF_RBP = 0;                                   // 50*(k,r0)
constexpr size_t OFF_RAP = OFF_RBP + NBT * 2 * 4;               // 100*(k,th0)
constexpr size_t OFF_RTP = OFF_RAP + NAT * 2 * 4;               // 200*(k,cp,sp,n)
constexpr size_t OFF_CC  = OFF_RTP + NTT * 4 * 4;               // [B][6000] f32
constexpr size_t OFF_BQ  = OFF_CC  + (size_t)BATCH * 6000 * 4;  // [B][2048] u16x4
constexpr size_t OFF_AQ  = OFF_BQ  + (size_t)BATCH * 8192 * 2;  // [B][2048] u16x4
constexpr size_t OFF_TQ  = OFF_AQ  + (size_t)BATCH * 8192 * 2;  // [B][2048] u16x8
constexpr size_t OFF_PT  = OFF_TQ  + (size_t)BATCH * 16384 * 2; // [6144] f32

__device__ __forceinline__ float acos_fast(float x) {
    // Abramowitz-Stegun 4.4.45, |err| <= 6.8e-5 rad (validated R9, absmax 0)
    float t = fabsf(x);
    float p = fmaf(t, -0.0187293f, 0.0742610f);
    p = fmaf(p, t, -0.2121144f);
    p = fmaf(p, t, 1.5707288f);
    float r = sqrtf(1.0f - t) * p;
    return (x >= 0.0f) ? r : (3.14159265358979f - r);
}

__global__ __launch_bounds__(256) void prep_kernel(
    const float* __restrict__ opt_pars,
    const float* __restrict__ bond_type,
    const float* __restrict__ angle_type,
    const float* __restrict__ tor_type,
    float* __restrict__ rbp, float* __restrict__ rap, float* __restrict__ rtp)
{
    const int i = threadIdx.x;
    if (i < NBT) {
        int idx = (int)bond_type[i];
        rbp[2*i+0] = opt_pars[3*idx+0];
        rbp[2*i+1] = opt_pars[3*idx+1];
    }
    if (i < NAT) {
        int idx = (int)angle_type[i];
        rap[2*i+0] = opt_pars[3*idx+0];
        rap[2*i+1] = opt_pars[3*idx+1];
    }
    if (i < NTT) {
        int idx = (int)tor_type[i];
        float p0 = opt_pars[3*idx+1];
        rtp[4*i+0] = opt_pars[3*idx+0];
        rtp[4*i+1] = cosf(p0);
        rtp[4*i+2] = sinf(p0);
        rtp[4*i+3] = opt_pars[3*idx+2];
    }
}

__global__ __launch_bounds__(256) void compact_kernel(
    const float* __restrict__ features,
    float* __restrict__ cc, unsigned short* __restrict__ bq,
    unsigned short* __restrict__ aq, unsigned short* __restrict__ tq)
{
    const unsigned gid = blockIdx.x * 256u + threadIdx.x;   // one thread/row
    const unsigned b   = gid / (unsigned)MAXLEN;
    const unsigned i   = gid - b * (unsigned)MAXLEN;

    const float* __restrict__ row = features + (size_t)b * MAXLEN * 9 + 9u * i + 5u;
    float vc = row[0];   // col 5 coord
    float vb = row[1];   // col 6 bond
    float va = row[2];   // col 7 angle
    float vt = row[3];   // col 8 torsion

    if (i < 6000u) cc[b * 6000u + i] = vc;
    if (i < 5997u) {                       // bonds: 3/term -> ushort4 padded
        unsigned t = i / 3u, slot = i - 3u * t;
        bq[b * 8192u + 4u * t + slot] = (unsigned short)(int)vb;
    }
    if (i < 7992u)                         // angles: 4/term, natural pack
        aq[b * 8192u + i] = (unsigned short)(int)va;
    if (i < 9985u) {                       // torsions: 5/term -> ushort8 padded
        unsigned t = i / 5u, slot = i - 5u * t;
        tq[b * 16384u + 8u * t + slot] = (unsigned short)(int)vt;
    }
}

__global__ __launch_bounds__(256) void energy_kernel(
    const float* __restrict__ cc,
    const ushort4* __restrict__ bq,        // [B][2048]
    const ushort4* __restrict__ aq,        // [B][2048]
    const ushort4* __restrict__ tq,        // [B][4096] (2 per term)
    const int*   __restrict__ lengths,
    const float* __restrict__ rbp,
    const float* __restrict__ rap,
    const float* __restrict__ rtp,
    float*       __restrict__ part)        // [NCH*256], idx = c*256+b
{
    const int idx = blockIdx.x;            // c*256 + b  (XCD = b%8)
    const int b   = idx & 255;
    const int c   = idx >> 8;              // 0..23
    const int tid = threadIdx.x;
    const int tglob = c * 256 + tid;       // padded concat term space [0,6144)
    const int type  = tglob >> 11;         // wave-uniform (2048-aligned)
    const int t     = tglob & 2047;

    const float* __restrict__ cb = cc + (size_t)b * 6000;
    float e = 0.0f;

    if (type == 0) {                       // ---- bond ----
        const int nb = lengths[b * 9 + 6] / 3;
        if (t < nb) {
            ushort4 q = bq[b * 2048 + t];
            int i = q.x, j = q.y, ty = q.z;
            float dx = cb[3*i+0] - cb[3*j+0];
            float dy = cb[3*i+1] - cb[3*j+1];
            float dz = cb[3*i+2] - cb[3*j+2];
            float r  = sqrtf(dx*dx + dy*dy + dz*dz + EPS);
            float d  = r - rbp[2*ty+1];
            e = rbp[2*ty+0] * d * d;
        }
    } else if (type == 1) {                // ---- angle ----
        const int na = lengths[b * 9 + 7] / 4;
        if (t < na) {
            ushort4 q = aq[b * 2048 + t];
            int i = q.x, j = q.y, k_ = q.z, ty = q.w;
            float jx = cb[3*j+0], jy = cb[3*j+1], jz = cb[3*j+2];
            float ux = cb[3*i+0] - jx, uy = cb[3*i+1] - jy, uz = cb[3*i+2] - jz;
            float vx = cb[3*k_+0] - jx, vy = cb[3*k_+1] - jy, vz = cb[3*k_+2] - jz;
            float uv = ux*vx + uy*vy + uz*vz;
            float uu = ux*ux + uy*uy + uz*uz;
            float vv = vx*vx + vy*vy + vz*vz;
            float cth = uv * rsqrtf((uu + EPS) * (vv + EPS));
            cth = fminf(fmaxf(cth, -1.0f + 1e-6f), 1.0f - 1e-6f);
            float d = acos_fast(cth) - rap[2*ty+1];
            e = rap[2*ty+0] * d * d;
        }
    } else {                               // ---- torsion ----
        const int nt = lengths[b * 9 + 8] / 5;
        if (t < nt) {
            ushort4 q0 = tq[b * 4096 + 2*t];
            ushort4 q1 = tq[b * 4096 + 2*t + 1];
            int i = q0.x, j = q0.y, k_ = q0.z, l = q0.w, ty = q1.x;
            float ix = cb[3*i+0],  iy = cb[3*i+1],  iz = cb[3*i+2];
            float jx = cb[3*j+0],  jy = cb[3*j+1],  jz = cb[3*j+2];
            float kx = cb[3*k_+0], ky = cb[3*k_+1], kz = cb[3*k_+2];
            float lx = cb[3*l+0],  ly = cb[3*l+1],  lz = cb[3*l+2];
            float b1x = jx - ix, b1y = jy - iy, b1z = jz - iz;
            float b2x = kx - jx, b2y = ky - jy, b2z = kz - jz;
            float b3x = lx - kx, b3y = ly - ky, b3z = lz - kz;
            float n1x = b1y*b2z - b1z*b2y;
            float n1y = b1z*b2x - b1x*b2z;
            float n1z = b1x*b2y - b1y*b2x;
            float n2x = b2y*b3z - b2z*b3y;
            float n2y = b2z*b3x - b2x*b3z;
            float n2z = b2x*b3y - b2y*b3x;
            float inv = rsqrtf(b2x*b2x + b2y*b2y + b2z*b2z + EPS);
            float hx = b2x * inv, hy = b2y * inv, hz = b2z * inv;
            float m1x = n1y*hz - n1z*hy;
            float m1y = n1z*hx - n1x*hz;
            float m1z = n1x*hy - n1y*hx;
            float sy = m1x*n2x + m1y*n2y + m1z*n2z;   // |n1||n2| sin(phi)
            float sx = n1x*n2x + n1y*n2y + n1z*n2z;   // |n1||n2| cos(phi)
            float rinv = rsqrtf(sx*sx + sy*sy + 1e-30f);
            float c1 = sx * rinv, s1 = sy * rinv;
            float c2 = fmaf(2.0f*c1, c1, -1.0f);
            float s2 = 2.0f * s1 * c1;
            float c3 = fmaf(2.0f*c1, c2, -c1);
            float s3 = fmaf(2.0f*c1, s2, -s1);
            float k  = rtp[4*ty+0];
            float cp = rtp[4*ty+1];
            float sp = rtp[4*ty+2];
            int   ni = (int)rtp[4*ty+3];
            float cn = (ni == 1) ? c1 : ((ni == 2) ? c2 : c3);
            float sn = (ni == 1) ? s1 : ((ni == 2) ? s2 : s3);
            e = k * (1.0f + cn * cp + sn * sp);
        }
    }

    // ---- block reduce (4 waves) -> part[idx] ----
    for (int off = 32; off > 0; off >>= 1)
        e += __shfl_down(e, off, 64);
    __shared__ float sw[4];
    const int wave = tid >> 6, lane = tid & 63;
    if (lane == 0) sw[wave] = e;
    __syncthreads();
    if (tid == 0)
        part[idx] = sw[0] + sw[1] + sw[2] + sw[3];
}

__global__ __launch_bounds__(256) void reduce_kernel(
    const float* __restrict__ part, float* __restrict__ out)
{
    const int b = threadIdx.x;
    float v = 0.0f;
    #pragma unroll
    for (int c = 0; c < NCH; ++c) v += part[c * 256 + b];  // coalesced
    out[b] = v;
}

extern "C" void kernel_launch(void* const* d_in, const int* in_sizes, int n_in,
                              void* d_out, int out_size, void* d_ws, size_t ws_size,
                              hipStream_t stream) {
    const float* features   = (const float*)d_in[0];
    const int*   lengths    = (const int*)  d_in[1];
    const float* opt_pars   = (const float*)d_in[2];
    const float* bond_type  = (const float*)d_in[3];
    const float* angle_type = (const float*)d_in[4];
    const float* tor_type   = (const float*)d_in[5];
    float* out = (float*)d_out;
    char*  ws  = (char*)d_ws;

    float*          rbp = (float*)(ws + OFF_RBP);
    float*          rap = (float*)(ws + OFF_RAP);
    float*          rtp = (float*)(ws + OFF_RTP);
    float*          cc  = (float*)(ws + OFF_CC);
    unsigned short* bq  = (unsigned short*)(ws + OFF_BQ);
    unsigned short* aq  = (unsigned short*)(ws + OFF_AQ);
    unsigned short* tq  = (unsigned short*)(ws + OFF_TQ);
    float*          pt  = (float*)(ws + OFF_PT);

    prep_kernel<<<1, 256, 0, stream>>>(opt_pars, bond_type, angle_type,
                                       tor_type, rbp, rap, rtp);
    compact_kernel<<<BATCH * MAXLEN / 256, 256, 0, stream>>>(
        features, cc, bq, aq, tq);
    energy_kernel<<<NCH * 256, 256, 0, stream>>>(
        cc, (const ushort4*)bq, (const ushort4*)aq, (const ushort4*)tq,
        lengths, rbp, rap, rtp, pt);
    reduce_kernel<<<1, 256, 0, stream>>>(pt, out);
}

// Round 11
// 144.349 us; speedup vs baseline: 1.1003x; 1.1003x over previous
//
#include <hip/hip_runtime.h>
#include <math.h>

// LocalEnergyOpt R11: pipelined fused kernel, 1 block/system (grid 256),
// 1024 threads. Ledger: fused=43us invariant to staging style (R8), trig
// (R9); split=45-48 invariant to occupancy (R5/R7/R10). Never tried: phase
// OVERLAP inside the block + compute ILP.
// Structure: rows [0,6000) hold ALL coords+bonds, angles t<1500, tors t<1200
// (78% of terms). Phase A stages them (60% of bytes); then group-1 compute
// is co-scheduled with the remaining 4000 rows' global loads (regs; compiler
// hoists independent loads above compute -> latency hidden); regs->LDS;
// barrier; group-2 (22% of terms). Compute upgrades: coords float4-padded
// in LDS (ds_read_b128, 3x fewer gather instrs), manual 2x term unroll
// (runtime-trip loops never unroll -> no ILP before), R9 trig-free math.

#define EBS 1024

constexpr int MAXLEN = 10000;
constexpr int NBT = 50, NAT = 100, NTT = 200;
constexpr float EPS = 1e-8f;

// LDS layout (bytes) — 88464 B -> 1 block/CU
constexpr int OFF_SCF = 0;                     // 2000 atoms * float4 (x,y,z,-)
constexpr int OFF_SB  = OFF_SCF + 8000 * 4;    // 2000 * ushort4 bonds (i,j,ty,-)
constexpr int OFF_SA  = OFF_SB  + 8000 * 2;    // 7992 u16 angles, natural 4/term
constexpr int OFF_ST4 = OFF_SA  + 8000 * 2;    // 2000 * ushort4 torsion ijkl
constexpr int OFF_STY = OFF_ST4 + 8000 * 2;    // 2000 u16 torsion type
constexpr int OFF_RBP = OFF_STY + 2000 * 2;    // 50*(k,r0)
constexpr int OFF_RAP = OFF_RBP + 100 * 4;     // 100*(k,th0)
constexpr int OFF_RTP = OFF_RAP + 200 * 4;     // 200*(k,cp,sp,n)
constexpr int OFF_SW  = OFF_RTP + 800 * 4;     // 16 f32 wave partials
constexpr int SMEM_BYTES = OFF_SW + 16 * 4;

__device__ __forceinline__ float acos_fast(float x) {
    // Abramowitz-Stegun 4.4.45, |err|<=6.8e-5 rad (validated R9/R10, absmax 0)
    float t = fabsf(x);
    float p = fmaf(t, -0.0187293f, 0.0742610f);
    p = fmaf(p, t, -0.2121144f);
    p = fmaf(p, t, 1.5707288f);
    float r = sqrtf(1.0f - t) * p;
    return (x >= 0.0f) ? r : (3.14159265358979f - r);
}

__global__ __launch_bounds__(EBS) void energy_kernel(
    const float* __restrict__ features,   // [B, 10000, 9]
    const int*   __restrict__ lengths,    // [B, 9]
    const float* __restrict__ opt_pars,   // [350, 3]
    const float* __restrict__ bond_type,  // [50]
    const float* __restrict__ angle_type, // [100]
    const float* __restrict__ tor_type,   // [200]
    float*       __restrict__ out)        // [B]
{
    extern __shared__ __align__(16) char smem[];
    float*          scf = (float*)(smem + OFF_SCF);
    const float4*   sc4 = (const float4*)(smem + OFF_SCF);
    unsigned short* sb  = (unsigned short*)(smem + OFF_SB);
    const ushort4*  sb4 = (const ushort4*)(smem + OFF_SB);
    unsigned short* sa  = (unsigned short*)(smem + OFF_SA);
    const ushort4*  sa4 = (const ushort4*)(smem + OFF_SA);
    unsigned short* st4 = (unsigned short*)(smem + OFF_ST4);
    const ushort4*  st44= (const ushort4*)(smem + OFF_ST4);
    unsigned short* sty = (unsigned short*)(smem + OFF_STY);
    float*          rbp = (float*)(smem + OFF_RBP);
    float*          rap = (float*)(smem + OFF_RAP);
    float*          rtp = (float*)(smem + OFF_RTP);
    float*          sw  = (float*)(smem + OFF_SW);

    const int b   = blockIdx.x;
    const int tid = threadIdx.x;
    const float* __restrict__ fb = features + (size_t)b * MAXLEN * 9;

    // ---- resolved param tables ----
    if (tid < NBT) {
        int idx = (int)bond_type[tid];
        rbp[2*tid+0] = opt_pars[3*idx+0];
        rbp[2*tid+1] = opt_pars[3*idx+1];
    } else if (tid < NBT + NAT) {
        int i = tid - NBT;
        int idx = (int)angle_type[i];
        rap[2*i+0] = opt_pars[3*idx+0];
        rap[2*i+1] = opt_pars[3*idx+1];
    } else if (tid < NBT + NAT + NTT) {
        int i = tid - NBT - NAT;
        int idx = (int)tor_type[i];
        float p0 = opt_pars[3*idx+1];
        rtp[4*i+0] = opt_pars[3*idx+0];
        rtp[4*i+1] = cosf(p0);
        rtp[4*i+2] = sinf(p0);
        rtp[4*i+3] = opt_pars[3*idx+2];
    }

    // ---- Phase A: stage rows [0,6000) — coords(all) + bonds(all) +
    //      angle rows<6000 (t<1500) + torsion rows<6000 (t<1200) ----
    #pragma unroll
    for (int k = 0; k < 6; ++k) {
        const int i = tid + k * EBS;
        if (i < 6000) {
            const float* __restrict__ row = fb + 9 * i + 5;
            float vc = row[0];
            float vb = row[1];
            float va = row[2];
            float vt = row[3];
            const int q3 = i / 3, r3 = i - 3 * q3;      // atom / dim; bond t / slot
            scf[4 * q3 + r3] = vc;
            if (i < 5997) sb[4 * q3 + r3] = (unsigned short)(int)vb;
            sa[i] = (unsigned short)(int)va;            // i < 6000 < 7992
            const int q5 = i / 5, r5 = i - 5 * q5;
            if (r5 < 4) st4[4 * q5 + r5] = (unsigned short)(int)vt;
            else        sty[q5]          = (unsigned short)(int)vt;
        }
    }
    __syncthreads();

    const int nb = lengths[b * 9 + 6] / 3;
    const int na = lengths[b * 9 + 7] / 4;
    const int nt = lengths[b * 9 + 8] / 5;

    // ---- term bodies (read LDS only) ----
    auto bond_e = [&](int t) -> float {
        ushort4 q = sb4[t];
        float4 pi = sc4[q.x], pj = sc4[q.y];
        float dx = pi.x - pj.x, dy = pi.y - pj.y, dz = pi.z - pj.z;
        float r  = sqrtf(dx*dx + dy*dy + dz*dz + EPS);
        float d  = r - rbp[2*q.z+1];
        return rbp[2*q.z+0] * d * d;
    };
    auto angle_e = [&](int t) -> float {
        ushort4 q = sa4[t];
        float4 pi = sc4[q.x], pj = sc4[q.y], pk = sc4[q.z];
        float ux = pi.x - pj.x, uy = pi.y - pj.y, uz = pi.z - pj.z;
        float vx = pk.x - pj.x, vy = pk.y - pj.y, vz = pk.z - pj.z;
        float uv = ux*vx + uy*vy + uz*vz;
        float uu = ux*ux + uy*uy + uz*uz;
        float vv = vx*vx + vy*vy + vz*vz;
        float cth = uv * rsqrtf((uu + EPS) * (vv + EPS));
        cth = fminf(fmaxf(cth, -1.0f + 1e-6f), 1.0f - 1e-6f);
        float d = acos_fast(cth) - rap[2*q.w+1];
        return rap[2*q.w+0] * d * d;
    };
    auto tor_e = [&](int t) -> float {
        ushort4 q = st44[t];
        int ty = sty[t];
        float4 pi = sc4[q.x], pj = sc4[q.y], pk = sc4[q.z], pl = sc4[q.w];
        float b1x = pj.x - pi.x, b1y = pj.y - pi.y, b1z = pj.z - pi.z;
        float b2x = pk.x - pj.x, b2y = pk.y - pj.y, b2z = pk.z - pj.z;
        float b3x = pl.x - pk.x, b3y = pl.y - pk.y, b3z = pl.z - pk.z;
        float n1x = b1y*b2z - b1z*b2y;
        float n1y = b1z*b2x - b1x*b2z;
        float n1z = b1x*b2y - b1y*b2x;
        float n2x = b2y*b3z - b2z*b3y;
        float n2y = b2z*b3x - b2x*b3z;
        float n2z = b2x*b3y - b2y*b3x;
        float inv = rsqrtf(b2x*b2x + b2y*b2y + b2z*b2z + EPS);
        float hx = b2x * inv, hy = b2y * inv, hz = b2z * inv;
        float m1x = n1y*hz - n1z*hy;
        float m1y = n1z*hx - n1x*hz;
        float m1z = n1x*hy - n1y*hx;
        float sy = m1x*n2x + m1y*n2y + m1z*n2z;   // |n1||n2| sin(phi)
        float sx = n1x*n2x + n1y*n2y + n1z*n2z;   // |n1||n2| cos(phi)
        float rinv = rsqrtf(sx*sx + sy*sy + 1e-30f);
        float c1 = sx * rinv, s1 = sy * rinv;
        float c2 = fmaf(2.0f*c1, c1, -1.0f);
        float s2 = 2.0f * s1 * c1;
        float c3 = fmaf(2.0f*c1, c2, -c1);
        float s3 = fmaf(2.0f*c1, s2, -s1);
        float k  = rtp[4*ty+0];
        float cp = rtp[4*ty+1];
        float sp = rtp[4*ty+2];
        int   ni = (int)rtp[4*ty+3];
        float cn = (ni == 1) ? c1 : ((ni == 2) ? c2 : c3);
        float sn = (ni == 1) ? s1 : ((ni == 2) ? s2 : s3);
        return k * (1.0f + cn * cp + sn * sp);
    };

    float acc = 0.0f;

    // ---- Phase B loads (rows [6000,10000), cols 7+8) issued here so the
    //      compiler overlaps them with group-1 compute below ----
    float pva[4], pvt[4];
    #pragma unroll
    for (int k = 0; k < 4; ++k) {
        const int i = 6000 + tid + k * EBS;
        if (i < MAXLEN) {
            const float* __restrict__ row = fb + 9 * i + 7;
            pva[k] = row[0];
            pvt[k] = row[1];
        }
    }

    // ---- group-1 compute: bonds(all) + angles t<1500 + tors t<1200 ----
    {
        int t0 = tid, t1 = tid + EBS;              // independent -> ILP
        float e0 = (t0 < nb) ? bond_e(t0) : 0.0f;
        float e1 = (t1 < nb) ? bond_e(t1) : 0.0f;
        acc += e0 + e1;
    }
    {
        const int lim = min(na, 1500);
        int t0 = tid, t1 = tid + EBS;
        float e0 = (t0 < lim) ? angle_e(t0) : 0.0f;
        float e1 = (t1 < lim) ? angle_e(t1) : 0.0f;
        acc += e0 + e1;
    }
    {
        const int lim = min(nt, 1200);
        int t0 = tid, t1 = tid + EBS;
        float e0 = (t0 < lim) ? tor_e(t0) : 0.0f;
        float e1 = (t1 < lim) ? tor_e(t1) : 0.0f;
        acc += e0 + e1;
    }

    // ---- Phase B write-back regs -> LDS ----
    #pragma unroll
    for (int k = 0; k < 4; ++k) {
        const int i = 6000 + tid + k * EBS;
        if (i < MAXLEN) {
            if (i < 7992) sa[i] = (unsigned short)(int)pva[k];
            if (i < 9985) {
                const int q5 = i / 5, r5 = i - 5 * q5;
                if (r5 < 4) st4[4 * q5 + r5] = (unsigned short)(int)pvt[k];
                else        sty[q5]          = (unsigned short)(int)pvt[k];
            }
        }
    }
    __syncthreads();

    // ---- group-2 compute: angles t in [1500,na), tors t in [1200,nt) ----
    {
        int t = 1500 + tid;
        if (t < na) acc += angle_e(t);
        int u = 1200 + tid;
        if (u < nt) acc += tor_e(u);
    }

    // ---- reduce: 64-lane shuffle, then cross-wave via LDS ----
    for (int off = 32; off > 0; off >>= 1)
        acc += __shfl_down(acc, off, 64);
    const int wave = tid >> 6, lane = tid & 63;
    if (lane == 0) sw[wave] = acc;
    __syncthreads();
    if (tid == 0) {
        float v = 0.0f;
        #pragma unroll
        for (int w = 0; w < EBS / 64; ++w) v += sw[w];
        out[b] = v;
    }
}

extern "C" void kernel_launch(void* const* d_in, const int* in_sizes, int n_in,
                              void* d_out, int out_size, void* d_ws, size_t ws_size,
                              hipStream_t stream) {
    const float* features   = (const float*)d_in[0];
    const int*   lengths    = (const int*)  d_in[1];
    const float* opt_pars   = (const float*)d_in[2];
    const float* bond_type  = (const float*)d_in[3];
    const float* angle_type = (const float*)d_in[4];
    const float* tor_type   = (const float*)d_in[5];
    float* out = (float*)d_out;

    // ~86.4 KB dynamic LDS (> 64 KB default); idempotent, capture-safe.
    hipFuncSetAttribute((const void*)energy_kernel,
                        hipFuncAttributeMaxDynamicSharedMemorySize, SMEM_BYTES);

    const int B = out_size;  // 256
    energy_kernel<<<B, EBS, SMEM_BYTES, stream>>>(
        features, lengths, opt_pars, bond_type, angle_type, tor_type, out);
}